// Round 15
// baseline (150.924 us; speedup 1.0000x reference)
//
#include <hip/hip_runtime.h>
#include <hip/hip_bf16.h>
#include <stdint.h>

#define NN 8192
#define FF 256

typedef unsigned short u16;
typedef __attribute__((ext_vector_type(4))) float f32x4;
typedef __attribute__((ext_vector_type(8))) short s16x8;
typedef __attribute__((ext_vector_type(8))) __bf16 bf16x8;

// round-half-up f32->bf16 (adj >= 0)
__device__ inline u16 bf_rhu(float f) {
  union { float f; unsigned u; } v; v.f = f;
  return (u16)((v.u + 0x8000u) >> 16);
}
// round-to-nearest-even f32->bf16
__device__ inline u16 f2bf_rne(float f) {
  union { float f; unsigned u; } v; v.f = f;
  unsigned r = v.u + 0x7FFFu + ((v.u >> 16) & 1u);
  return (u16)(r >> 16);
}
__device__ inline float bf2f(u16 h) {
  union { unsigned u; float f; } v; v.u = (unsigned)h << 16; return v.f;
}

__device__ inline void gld_lds16(const void* g, void* l) {
  __builtin_amdgcn_global_load_lds(
      (const __attribute__((address_space(1))) void*)g,
      (__attribute__((address_space(3))) void*)l, 16, 0, 0);
}

// ---------------- K0: Wb = bf16(W), layout unchanged [o][f] ----------------
__global__ __launch_bounds__(256) void k_wb(const float* __restrict__ W,
                                            u16* __restrict__ Wb) {
  int idx = (blockIdx.x * 256 + threadIdx.x) * 4;
  f32x4 v = *reinterpret_cast<const f32x4*>(W + idx);
  ushort4 o;
  o.x = f2bf_rne(v.x); o.y = f2bf_rne(v.y); o.z = f2bf_rne(v.z); o.w = f2bf_rne(v.w);
  *reinterpret_cast<ushort4*>(Wb + idx) = o;
}

// -------- K1: adjbT = bf16(adj) in GEMM-native TILED+SWIZZLED layout;
//          prows[kc][row] = partial rowsum over this kc's 2048 cols --------
// Tile image: tileIdx = (bm*4+kc)*32+kt holds [128][64] bf16 with slot
// r*8+(c8^(r&7)) -- exactly the gemm's LDS image, so gemm A-staging is a
// contiguous 16KB linear burst per K-step (granule problem eliminated).
// Block (kc,bm,rh): 32 rows x 2048 cols; reads 8KB/row contiguous (NT),
// writes 32 x 1KB contiguous slices per 8-row group via LDS transpose.
__global__ __launch_bounds__(256) void k_pass1(const float* __restrict__ adj,
                                               u16* __restrict__ adjbT,
                                               float* __restrict__ prows) {
  __shared__ __align__(16) u16 ldsT[32][512];    // 32 KB: [kt][slice of 8 rows]
  __shared__ float rsW[4][8];
  const int kc = blockIdx.x;            // 0..3
  const int bm = blockIdx.y;            // 0..63
  const int rh = blockIdx.z;            // 0..3
  const size_t i0 = (size_t)bm * 128;
  const int k0 = kc * 2048;
  const int t = threadIdx.x, lane = t & 63, w = t >> 6;
  const int kt = t >> 3, c8 = t & 7;    // this thread's tile / col-chunk in phase 1

  for (int gg = 0; gg < 4; ++gg) {
    const int g = rh * 4 + gg;          // 8-row group 0..15
    float ps[8];
    // ---- phase 1: read 8 rows (8KB contiguous each), cvt, stage LDS ----
#pragma unroll
    for (int r8 = 0; r8 < 8; ++r8) {
      const int row = g * 8 + r8;
      const float* gp = adj + (i0 + row) * (size_t)NN + k0 + t * 8;
      f32x4 v0 = __builtin_nontemporal_load(reinterpret_cast<const f32x4*>(gp));
      f32x4 v1 = __builtin_nontemporal_load(reinterpret_cast<const f32x4*>(gp) + 1);
      s16x8 o;
#pragma unroll
      for (int e = 0; e < 4; ++e) o[e] = (short)bf_rhu(v0[e]);
#pragma unroll
      for (int e = 0; e < 4; ++e) o[4 + e] = (short)bf_rhu(v1[e]);
      *reinterpret_cast<s16x8*>(&ldsT[kt][(r8 * 8 + (c8 ^ r8)) * 8]) = o;
      ps[r8] = ((v0.x + v0.y) + (v0.z + v0.w)) + ((v1.x + v1.y) + (v1.z + v1.w));
    }
    // wave-reduce each row partial
#pragma unroll
    for (int r8 = 0; r8 < 8; ++r8) {
#pragma unroll
      for (int o = 32; o > 0; o >>= 1) ps[r8] += __shfl_down(ps[r8], o);
    }
    if (lane == 0) {
#pragma unroll
      for (int r8 = 0; r8 < 8; ++r8) rsW[w][r8] = ps[r8];
    }
    __syncthreads();
    // ---- phase 2: write 32 tiles x 1KB contiguous; store row partials ----
#pragma unroll
    for (int q = 0; q < 8; ++q) {
      int c = q * 256 + t;               // 0..2047 16B-chunks
      int kt2 = c >> 6, sl = c & 63;
      size_t dst = ((size_t)((bm * 4 + kc) * 32 + kt2)) * 8192
                 + (size_t)g * 512 + sl * 8;
      *reinterpret_cast<s16x8*>(adjbT + dst) =
          *reinterpret_cast<const s16x8*>(&ldsT[kt2][sl * 8]);
    }
    if (t < 8) {
      float s = (rsW[0][t] + rsW[1][t]) + (rsW[2][t] + rsW[3][t]);
      prows[(size_t)kc * NN + i0 + g * 8 + t] = s;
    }
    __syncthreads();
  }
}

// ---------------- K1b: dis[i] = rsqrt( sum_kc prows ) ----------------
__global__ __launch_bounds__(256) void k_dis(const float* __restrict__ prows,
                                             float* __restrict__ dis) {
  int i = blockIdx.x * 256 + threadIdx.x;
  float s = (prows[i] + prows[NN + i]) + (prows[2 * NN + i] + prows[3 * NN + i]);
  dis[i] = s > 0.f ? 1.0f / sqrtf(s) : 0.f;
}

// ------- K2: xwT[fo][j] = bf16( dis[j] * (x @ W^T)[j][fo] )  (transposed) -------
// (R4-R14-verified) block: 32 j-rows x 256 fo, 4 waves.
__global__ __launch_bounds__(256) void k_xwt(const float* __restrict__ x,
                                             const float* __restrict__ dis,
                                             const u16* __restrict__ Wb,
                                             u16* __restrict__ xwT) {
  __shared__ __align__(16) u16 As[32 * 256];     // slot = r*32 + (c8^(r&7))
  __shared__ __align__(16) u16 LT[256 * 34];     // [fo][j], pad 34
  const int j0 = blockIdx.x * 32;
  const int t = threadIdx.x, lane = t & 63, w = t >> 6;
  const int wr = w >> 1, wc = w & 1;

#pragma unroll
  for (int q = 0; q < 4; ++q) {
    int chunk = t * 4 + q;           // 0..1023
    int r = chunk >> 5, c8 = chunk & 31;
    const float* g = x + (size_t)(j0 + r) * FF + c8 * 8;
    f32x4 v0 = *reinterpret_cast<const f32x4*>(g);
    f32x4 v1 = *reinterpret_cast<const f32x4*>(g + 4);
    float d = dis[j0 + r];
    s16x8 o;
#pragma unroll
    for (int e = 0; e < 4; ++e) o[e] = (short)f2bf_rne(v0[e] * d);
#pragma unroll
    for (int e = 0; e < 4; ++e) o[4 + e] = (short)f2bf_rne(v1[e] * d);
    *reinterpret_cast<s16x8*>(&As[(r * 32 + (c8 ^ (r & 7))) * 8]) = o;
  }
  __syncthreads();

  f32x4 occ[8] = {};
#pragma unroll
  for (int ks = 0; ks < 8; ++ks) {
    int cg = ks * 4 + (lane >> 4);
    int ar = wr * 16 + (lane & 15);
    bf16x8 af = __builtin_bit_cast(bf16x8,
        *reinterpret_cast<const s16x8*>(&As[(ar * 32 + (cg ^ (ar & 7))) * 8]));
#pragma unroll
    for (int ni = 0; ni < 8; ++ni) {
      int n = wc * 128 + ni * 16 + (lane & 15);
      bf16x8 bfv = __builtin_bit_cast(bf16x8,
          *reinterpret_cast<const s16x8*>(Wb + (size_t)n * FF + cg * 8));
      occ[ni] = __builtin_amdgcn_mfma_f32_16x16x32_bf16(af, bfv, occ[ni], 0, 0, 0);
    }
  }

  int rj0 = wr * 16 + (lane >> 4) * 4;
#pragma unroll
  for (int ni = 0; ni < 8; ++ni) {
    int c = wc * 128 + ni * 16 + (lane & 15);
#pragma unroll
    for (int e = 0; e < 4; ++e)
      LT[c * 34 + rj0 + e] = f2bf_rne(occ[ni][e]);
  }
  __syncthreads();

  {
    int fo = t, base = fo * 34;
    u16* dst = xwT + (size_t)fo * NN + j0;
#pragma unroll
    for (int q = 0; q < 4; ++q) {
      ushort4 vv;
      vv.x = LT[base + q * 8 + 0]; vv.y = LT[base + q * 8 + 1];
      vv.z = LT[base + q * 8 + 2]; vv.w = LT[base + q * 8 + 3];
      ushort4 vw;
      vw.x = LT[base + q * 8 + 4]; vw.y = LT[base + q * 8 + 5];
      vw.z = LT[base + q * 8 + 6]; vw.w = LT[base + q * 8 + 7];
      *reinterpret_cast<ushort4*>(dst + q * 8) = vv;
      *reinterpret_cast<ushort4*>(dst + q * 8 + 4) = vw;
    }
  }
}

// -------- K3: split-K GEMM  partb[kc] = bf16( adjbT_tile @ xwT^T ) --------
// R14 config (BM=BN=128, BK=64, 256 thr, 4 waves 2x2 of 64x64, acc 4x4,
// 64 KB LDS -> 2 blocks/CU, grid (4,2,64): each XCD owns one (kc,bn)).
// A-STAGE is now a LINEAR 16KB burst from the tiled adjbT (swizzle pre-baked
// by k_pass1) -- the sub-page strided-granule pattern is gone.
__global__ __launch_bounds__(256, 2) void k_gemm1(const u16* __restrict__ adjbT,
                                                  const u16* __restrict__ xwT,
                                                  u16* __restrict__ partb) {
  __shared__ __align__(16) u16 As[2][128 * 64];   // 16 KB x2
  __shared__ __align__(16) u16 Bs[2][128 * 64];   // 16 KB x2
  const int kc = blockIdx.x;            // 0..3
  const int bn = blockIdx.y;            // 0..1
  const int bm = blockIdx.z;            // 0..63
  const size_t i0 = (size_t)bm * 128;
  const int k0 = kc * 2048;
  const int n0 = bn * 128;
  const int t = threadIdx.x;
  const int lane = t & 63;
  const int w = t >> 6;                 // 0..3
  const int wr = w >> 1, wc = w & 1;    // 2x2 waves, 64x64 each

  f32x4 acc[4][4] = {};

  auto STAGE = [&](int buf, int kt) {
    // A: contiguous 16KB tile, linear src -> linear dest
    const u16* atile = adjbT + ((size_t)((bm * 4 + kc) * 32 + kt)) * 8192;
#pragma unroll
    for (int q = 0; q < 4; ++q) {
      int s = q * 256 + t;
      gld_lds16(atile + s * 8, &As[buf][s * 8]);
    }
    // B: 128x64 bf16, pre-swizzled source (unchanged)
    const int kbase = k0 + kt * 64;
#pragma unroll
    for (int q = 0; q < 4; ++q) {
      int s = q * 256 + t;
      int r = s >> 3, c8 = s & 7;
      gld_lds16(xwT + (size_t)(n0 + r) * NN + kbase + ((c8 ^ (r & 7)) * 8),
                &Bs[buf][s * 8]);
    }
  };
  auto compute = [&](int buf) {
#pragma unroll
    for (int kk = 0; kk < 2; ++kk) {
      const int cg = kk * 4 + (lane >> 4);
      bf16x8 af[4], bfv[4];
#pragma unroll
      for (int mi = 0; mi < 4; ++mi) {
        int r = wr * 64 + mi * 16 + (lane & 15);
        af[mi] = __builtin_bit_cast(bf16x8,
            *reinterpret_cast<const s16x8*>(&As[buf][(r * 8 + (cg ^ (r & 7))) * 8]));
      }
#pragma unroll
      for (int ni = 0; ni < 4; ++ni) {
        int n = wc * 64 + ni * 16 + (lane & 15);
        bfv[ni] = __builtin_bit_cast(bf16x8,
            *reinterpret_cast<const s16x8*>(&Bs[buf][(n * 8 + (cg ^ (n & 7))) * 8]));
      }
#pragma unroll
      for (int mi = 0; mi < 4; ++mi)
#pragma unroll
        for (int ni = 0; ni < 4; ++ni)
          acc[mi][ni] = __builtin_amdgcn_mfma_f32_16x16x32_bf16(af[mi], bfv[ni], acc[mi][ni], 0, 0, 0);
    }
  };

  STAGE(0, 0);
  __syncthreads();
#pragma unroll 2
  for (int kt = 0; kt < 32; ++kt) {
    int buf = kt & 1;
    if (kt + 1 < 32) STAGE(buf ^ 1, kt + 1);
    compute(buf);
    __syncthreads();
  }

  u16* pout = partb + (size_t)kc * ((size_t)NN * FF);
#pragma unroll
  for (int mi = 0; mi < 4; ++mi) {
    int rbase = wr * 64 + mi * 16 + ((lane >> 4) * 4);
#pragma unroll
    for (int ni = 0; ni < 4; ++ni) {
      int cc = n0 + wc * 64 + ni * 16 + (lane & 15);
#pragma unroll
      for (int e = 0; e < 4; ++e)
        pout[(i0 + rbase + e) * FF + cc] = f2bf_rne(acc[mi][ni][e]);
    }
  }
}

// -------- K4: out = dis_i * sum_kc partb + bias  (bf16 slices, fp32 out) --------
__global__ __launch_bounds__(256) void k_out_lite(const u16* __restrict__ partb,
                                                  const float* __restrict__ dis,
                                                  const float* __restrict__ bias,
                                                  float* __restrict__ out) {
  size_t base = ((size_t)blockIdx.x * 256 + threadIdx.x) * 8;
  int i = (int)(base >> 8);
  int c = (int)(base & 255);
  const size_t SL = (size_t)NN * FF;
  s16x8 a0 = *reinterpret_cast<const s16x8*>(partb + base);
  s16x8 a1 = *reinterpret_cast<const s16x8*>(partb + SL + base);
  s16x8 a2 = *reinterpret_cast<const s16x8*>(partb + 2 * SL + base);
  s16x8 a3 = *reinterpret_cast<const s16x8*>(partb + 3 * SL + base);
  float d = dis[i];
  f32x4 o0, o1;
#pragma unroll
  for (int e = 0; e < 4; ++e) {
    float s = (bf2f((u16)a0[e]) + bf2f((u16)a1[e]))
            + (bf2f((u16)a2[e]) + bf2f((u16)a3[e]));
    o0[e] = s * d + bias[c + e];
  }
#pragma unroll
  for (int e = 0; e < 4; ++e) {
    float s = (bf2f((u16)a0[4 + e]) + bf2f((u16)a1[4 + e]))
            + (bf2f((u16)a2[4 + e]) + bf2f((u16)a3[4 + e]));
    o1[e] = s * d + bias[c + 4 + e];
  }
  *reinterpret_cast<f32x4*>(out + base) = o0;
  *reinterpret_cast<f32x4*>(out + base + 4) = o1;
}

extern "C" void kernel_launch(void* const* d_in, const int* in_sizes, int n_in,
                              void* d_out, int out_size, void* d_ws, size_t ws_size,
                              hipStream_t stream) {
  (void)in_sizes; (void)n_in; (void)out_size; (void)ws_size;
  const float* x   = (const float*)d_in[0];
  const float* adj = (const float*)d_in[1];
  const float* W   = (const float*)d_in[2];
  const float* b   = (const float*)d_in[3];
  float* out = (float*)d_out;
  char* ws = (char*)d_ws;

  // ws: dis 32KB @0 | Wb 128KB @64KB | prows 128KB @256KB | xwT 4MB @1MB
  //     | partb 16MB @8MB | adjbT 128MB @48MB
  float* dis   = (float*)ws;
  u16*   Wb    = (u16*)(ws + (64u << 10));
  float* prows = (float*)(ws + (256u << 10));
  u16*   xwT   = (u16*)(ws + (1u << 20));
  u16*   partb = (u16*)(ws + (8u << 20));
  u16*   adjbT = (u16*)(ws + (48u << 20));

  k_wb<<<dim3(64), dim3(256), 0, stream>>>(W, Wb);
  k_pass1<<<dim3(4, 64, 4), dim3(256), 0, stream>>>(adj, adjbT, prows);
  k_dis<<<dim3(32), dim3(256), 0, stream>>>(prows, dis);
  k_xwt<<<dim3(256), dim3(256), 0, stream>>>(x, dis, Wb, xwT);
  k_gemm1<<<dim3(4, 2, 64), dim3(256), 0, stream>>>(adjbT, xwT, partb);
  k_out_lite<<<dim3(1024), dim3(256), 0, stream>>>(partb, dis, b, out);
}

// Round 16
// 143.149 us; speedup vs baseline: 1.0543x; 1.0543x over previous
//
#include <hip/hip_runtime.h>
#include <hip/hip_bf16.h>
#include <stdint.h>

#define NN 8192
#define FF 256

typedef unsigned short u16;
typedef __attribute__((ext_vector_type(4))) float f32x4;
typedef __attribute__((ext_vector_type(8))) short s16x8;
typedef __attribute__((ext_vector_type(8))) __bf16 bf16x8;

// round-half-up f32->bf16 (adj >= 0)
__device__ inline u16 bf_rhu(float f) {
  union { float f; unsigned u; } v; v.f = f;
  return (u16)((v.u + 0x8000u) >> 16);
}
// round-to-nearest-even f32->bf16
__device__ inline u16 f2bf_rne(float f) {
  union { float f; unsigned u; } v; v.f = f;
  unsigned r = v.u + 0x7FFFu + ((v.u >> 16) & 1u);
  return (u16)(r >> 16);
}
__device__ inline float bf2f(u16 h) {
  union { unsigned u; float f; } v; v.u = (unsigned)h << 16; return v.f;
}

__device__ inline void gld_lds16(const void* g, void* l) {
  __builtin_amdgcn_global_load_lds(
      (const __attribute__((address_space(1))) void*)g,
      (__attribute__((address_space(3))) void*)l, 16, 0, 0);
}

// ---------------- K0: Wb = bf16(W), layout unchanged [o][f] ----------------
__global__ __launch_bounds__(256) void k_wb(const float* __restrict__ W,
                                            u16* __restrict__ Wb) {
  int idx = (blockIdx.x * 256 + threadIdx.x) * 4;
  f32x4 v = *reinterpret_cast<const f32x4*>(W + idx);
  ushort4 o;
  o.x = f2bf_rne(v.x); o.y = f2bf_rne(v.y); o.z = f2bf_rne(v.z); o.w = f2bf_rne(v.w);
  *reinterpret_cast<ushort4*>(Wb + idx) = o;
}

// ---- K1: one row/block (R11's proven 63us structure): rowsum -> dis;
//      adjbT = bf16(adj) scatter-written DIRECTLY in the gemm's tiled+swizzled
//      image (verified correct by R15): tile=(bm*4+kc)*32+kt [16KB], slot =
//      rloc*8 + (c8^(rloc&7)). Per wave: 8 regions x 128B (2 cache lines each,
//      permuted within) -- L2 absorbs; no LDS, no extra syncs vs R11. ----
__global__ __launch_bounds__(256) void k_pass1(const float* __restrict__ adj,
                                               u16* __restrict__ adjbT,
                                               float* __restrict__ dis) {
  const int row = blockIdx.x;
  const int t = threadIdx.x;
  const f32x4* p = reinterpret_cast<const f32x4*>(adj + (size_t)row * NN);
  const int rloc = row & 127;
  const int bm = row >> 7;
  const int r7 = rloc & 7;
  float s = 0.f;
#pragma unroll
  for (int q = 0; q < 4; ++q) {
    int c = q * 256 + t;                 // 16B bf16 col-chunk id, 0..1023
    f32x4 v0 = __builtin_nontemporal_load(p + c * 2);
    f32x4 v1 = __builtin_nontemporal_load(p + c * 2 + 1);
    s16x8 o;
#pragma unroll
    for (int e = 0; e < 4; ++e) o[e] = (short)bf_rhu(v0[e]);
#pragma unroll
    for (int e = 0; e < 4; ++e) o[4 + e] = (short)bf_rhu(v1[e]);
    int kc = c >> 8, kt = (c >> 3) & 31, c8 = c & 7;
    size_t dst = ((size_t)((bm * 4 + kc) * 32 + kt)) * 8192
               + (size_t)(rloc * 8 + (c8 ^ r7)) * 8;
    *reinterpret_cast<s16x8*>(adjbT + dst) = o;
    s += ((v0.x + v0.y) + (v0.z + v0.w)) + ((v1.x + v1.y) + (v1.z + v1.w));
  }
#pragma unroll
  for (int o = 32; o > 0; o >>= 1) s += __shfl_down(s, o);
  __shared__ float red[4];
  if ((t & 63) == 0) red[t >> 6] = s;
  __syncthreads();
  if (t == 0) {
    float tot = (red[0] + red[1]) + (red[2] + red[3]);
    dis[row] = tot > 0.f ? 1.0f / sqrtf(tot) : 0.f;
  }
}

// ------- K2: xwT[fo][j] = bf16( dis[j] * (x @ W^T)[j][fo] )  (transposed) -------
// (R4-R15-verified) block: 32 j-rows x 256 fo, 4 waves.
__global__ __launch_bounds__(256) void k_xwt(const float* __restrict__ x,
                                             const float* __restrict__ dis,
                                             const u16* __restrict__ Wb,
                                             u16* __restrict__ xwT) {
  __shared__ __align__(16) u16 As[32 * 256];     // slot = r*32 + (c8^(r&7))
  __shared__ __align__(16) u16 LT[256 * 34];     // [fo][j], pad 34
  const int j0 = blockIdx.x * 32;
  const int t = threadIdx.x, lane = t & 63, w = t >> 6;
  const int wr = w >> 1, wc = w & 1;

#pragma unroll
  for (int q = 0; q < 4; ++q) {
    int chunk = t * 4 + q;           // 0..1023
    int r = chunk >> 5, c8 = chunk & 31;
    const float* g = x + (size_t)(j0 + r) * FF + c8 * 8;
    f32x4 v0 = *reinterpret_cast<const f32x4*>(g);
    f32x4 v1 = *reinterpret_cast<const f32x4*>(g + 4);
    float d = dis[j0 + r];
    s16x8 o;
#pragma unroll
    for (int e = 0; e < 4; ++e) o[e] = (short)f2bf_rne(v0[e] * d);
#pragma unroll
    for (int e = 0; e < 4; ++e) o[4 + e] = (short)f2bf_rne(v1[e] * d);
    *reinterpret_cast<s16x8*>(&As[(r * 32 + (c8 ^ (r & 7))) * 8]) = o;
  }
  __syncthreads();

  f32x4 occ[8] = {};
#pragma unroll
  for (int ks = 0; ks < 8; ++ks) {
    int cg = ks * 4 + (lane >> 4);
    int ar = wr * 16 + (lane & 15);
    bf16x8 af = __builtin_bit_cast(bf16x8,
        *reinterpret_cast<const s16x8*>(&As[(ar * 32 + (cg ^ (ar & 7))) * 8]));
#pragma unroll
    for (int ni = 0; ni < 8; ++ni) {
      int n = wc * 128 + ni * 16 + (lane & 15);
      bf16x8 bfv = __builtin_bit_cast(bf16x8,
          *reinterpret_cast<const s16x8*>(Wb + (size_t)n * FF + cg * 8));
      occ[ni] = __builtin_amdgcn_mfma_f32_16x16x32_bf16(af, bfv, occ[ni], 0, 0, 0);
    }
  }

  int rj0 = wr * 16 + (lane >> 4) * 4;
#pragma unroll
  for (int ni = 0; ni < 8; ++ni) {
    int c = wc * 128 + ni * 16 + (lane & 15);
#pragma unroll
    for (int e = 0; e < 4; ++e)
      LT[c * 34 + rj0 + e] = f2bf_rne(occ[ni][e]);
  }
  __syncthreads();

  {
    int fo = t, base = fo * 34;
    u16* dst = xwT + (size_t)fo * NN + j0;
#pragma unroll
    for (int q = 0; q < 4; ++q) {
      ushort4 vv;
      vv.x = LT[base + q * 8 + 0]; vv.y = LT[base + q * 8 + 1];
      vv.z = LT[base + q * 8 + 2]; vv.w = LT[base + q * 8 + 3];
      ushort4 vw;
      vw.x = LT[base + q * 8 + 4]; vw.y = LT[base + q * 8 + 5];
      vw.z = LT[base + q * 8 + 6]; vw.w = LT[base + q * 8 + 7];
      *reinterpret_cast<ushort4*>(dst + q * 8) = vv;
      *reinterpret_cast<ushort4*>(dst + q * 8 + 4) = vw;
    }
  }
}

// -------- K3: split-K GEMM  partb[kc] = bf16( adjbT_tile @ xwT^T ) --------
// (R15-verified) BM=BN=128, BK=64, 256 thr, 4 waves 2x2 of 64x64, acc 4x4,
// 64 KB LDS -> 2 blocks/CU, grid (4,2,64): each XCD owns one (kc,bn).
// A-STAGE = linear 16KB burst from tiled adjbT (swizzle pre-baked).
__global__ __launch_bounds__(256, 2) void k_gemm1(const u16* __restrict__ adjbT,
                                                  const u16* __restrict__ xwT,
                                                  u16* __restrict__ partb) {
  __shared__ __align__(16) u16 As[2][128 * 64];   // 16 KB x2
  __shared__ __align__(16) u16 Bs[2][128 * 64];   // 16 KB x2
  const int kc = blockIdx.x;            // 0..3
  const int bn = blockIdx.y;            // 0..1
  const int bm = blockIdx.z;            // 0..63
  const size_t i0 = (size_t)bm * 128;
  const int k0 = kc * 2048;
  const int n0 = bn * 128;
  const int t = threadIdx.x;
  const int lane = t & 63;
  const int w = t >> 6;                 // 0..3
  const int wr = w >> 1, wc = w & 1;    // 2x2 waves, 64x64 each

  f32x4 acc[4][4] = {};

  auto STAGE = [&](int buf, int kt) {
    // A: contiguous 16KB tile, linear src -> linear dest
    const u16* atile = adjbT + ((size_t)((bm * 4 + kc) * 32 + kt)) * 8192;
#pragma unroll
    for (int q = 0; q < 4; ++q) {
      int s = q * 256 + t;
      gld_lds16(atile + s * 8, &As[buf][s * 8]);
    }
    // B: 128x64 bf16, pre-swizzled source
    const int kbase = k0 + kt * 64;
#pragma unroll
    for (int q = 0; q < 4; ++q) {
      int s = q * 256 + t;
      int r = s >> 3, c8 = s & 7;
      gld_lds16(xwT + (size_t)(n0 + r) * NN + kbase + ((c8 ^ (r & 7)) * 8),
                &Bs[buf][s * 8]);
    }
  };
  auto compute = [&](int buf) {
#pragma unroll
    for (int kk = 0; kk < 2; ++kk) {
      const int cg = kk * 4 + (lane >> 4);
      bf16x8 af[4], bfv[4];
#pragma unroll
      for (int mi = 0; mi < 4; ++mi) {
        int r = wr * 64 + mi * 16 + (lane & 15);
        af[mi] = __builtin_bit_cast(bf16x8,
            *reinterpret_cast<const s16x8*>(&As[buf][(r * 8 + (cg ^ (r & 7))) * 8]));
      }
#pragma unroll
      for (int ni = 0; ni < 4; ++ni) {
        int n = wc * 64 + ni * 16 + (lane & 15);
        bfv[ni] = __builtin_bit_cast(bf16x8,
            *reinterpret_cast<const s16x8*>(&Bs[buf][(n * 8 + (cg ^ (n & 7))) * 8]));
      }
#pragma unroll
      for (int mi = 0; mi < 4; ++mi)
#pragma unroll
        for (int ni = 0; ni < 4; ++ni)
          acc[mi][ni] = __builtin_amdgcn_mfma_f32_16x16x32_bf16(af[mi], bfv[ni], acc[mi][ni], 0, 0, 0);
    }
  };

  STAGE(0, 0);
  __syncthreads();
#pragma unroll 2
  for (int kt = 0; kt < 32; ++kt) {
    int buf = kt & 1;
    if (kt + 1 < 32) STAGE(buf ^ 1, kt + 1);
    compute(buf);
    __syncthreads();
  }

  u16* pout = partb + (size_t)kc * ((size_t)NN * FF);
#pragma unroll
  for (int mi = 0; mi < 4; ++mi) {
    int rbase = wr * 64 + mi * 16 + ((lane >> 4) * 4);
#pragma unroll
    for (int ni = 0; ni < 4; ++ni) {
      int cc = n0 + wc * 64 + ni * 16 + (lane & 15);
#pragma unroll
      for (int e = 0; e < 4; ++e)
        pout[(i0 + rbase + e) * FF + cc] = f2bf_rne(acc[mi][ni][e]);
    }
  }
}

// -------- K4: out = dis_i * sum_kc partb + bias  (bf16 slices, fp32 out) --------
__global__ __launch_bounds__(256) void k_out_lite(const u16* __restrict__ partb,
                                                  const float* __restrict__ dis,
                                                  const float* __restrict__ bias,
                                                  float* __restrict__ out) {
  size_t base = ((size_t)blockIdx.x * 256 + threadIdx.x) * 8;
  int i = (int)(base >> 8);
  int c = (int)(base & 255);
  const size_t SL = (size_t)NN * FF;
  s16x8 a0 = *reinterpret_cast<const s16x8*>(partb + base);
  s16x8 a1 = *reinterpret_cast<const s16x8*>(partb + SL + base);
  s16x8 a2 = *reinterpret_cast<const s16x8*>(partb + 2 * SL + base);
  s16x8 a3 = *reinterpret_cast<const s16x8*>(partb + 3 * SL + base);
  float d = dis[i];
  f32x4 o0, o1;
#pragma unroll
  for (int e = 0; e < 4; ++e) {
    float s = (bf2f((u16)a0[e]) + bf2f((u16)a1[e]))
            + (bf2f((u16)a2[e]) + bf2f((u16)a3[e]));
    o0[e] = s * d + bias[c + e];
  }
#pragma unroll
  for (int e = 0; e < 4; ++e) {
    float s = (bf2f((u16)a0[4 + e]) + bf2f((u16)a1[4 + e]))
            + (bf2f((u16)a2[4 + e]) + bf2f((u16)a3[4 + e]));
    o1[e] = s * d + bias[c + 4 + e];
  }
  *reinterpret_cast<f32x4*>(out + base) = o0;
  *reinterpret_cast<f32x4*>(out + base + 4) = o1;
}

extern "C" void kernel_launch(void* const* d_in, const int* in_sizes, int n_in,
                              void* d_out, int out_size, void* d_ws, size_t ws_size,
                              hipStream_t stream) {
  (void)in_sizes; (void)n_in; (void)out_size; (void)ws_size;
  const float* x   = (const float*)d_in[0];
  const float* adj = (const float*)d_in[1];
  const float* W   = (const float*)d_in[2];
  const float* b   = (const float*)d_in[3];
  float* out = (float*)d_out;
  char* ws = (char*)d_ws;

  // ws: dis 32KB @0 | Wb 128KB @64KB | xwT 4MB @1MB | partb 16MB @8MB | adjbT 128MB @48MB
  float* dis   = (float*)ws;
  u16*   Wb    = (u16*)(ws + (64u << 10));
  u16*   xwT   = (u16*)(ws + (1u << 20));
  u16*   partb = (u16*)(ws + (8u << 20));
  u16*   adjbT = (u16*)(ws + (48u << 20));

  k_wb<<<dim3(64), dim3(256), 0, stream>>>(W, Wb);
  k_pass1<<<dim3(8192), dim3(256), 0, stream>>>(adj, adjbT, dis);
  k_xwt<<<dim3(256), dim3(256), 0, stream>>>(x, dis, Wb, xwT);
  k_gemm1<<<dim3(4, 2, 64), dim3(256), 0, stream>>>(adjbT, xwT, partb);
  k_out_lite<<<dim3(1024), dim3(256), 0, stream>>>(partb, dis, b, out);
}

// Round 17
// 128.133 us; speedup vs baseline: 1.1779x; 1.1172x over previous
//
#include <hip/hip_runtime.h>
#include <hip/hip_bf16.h>
#include <stdint.h>

#define NN 8192
#define FF 256

typedef unsigned short u16;
typedef __attribute__((ext_vector_type(4))) float f32x4;
typedef __attribute__((ext_vector_type(8))) short s16x8;
typedef __attribute__((ext_vector_type(8))) __bf16 bf16x8;

// round-to-nearest-even f32->bf16 (cold paths)
__device__ inline u16 f2bf_rne(float f) {
  union { float f; unsigned u; } v; v.f = f;
  unsigned r = v.u + 0x7FFFu + ((v.u >> 16) & 1u);
  return (u16)(r >> 16);
}
__device__ inline float bf2f(u16 h) {
  union { unsigned u; float f; } v; v.u = (unsigned)h << 16; return v.f;
}

__device__ inline void gld_lds16(const void* g, void* l) {
  __builtin_amdgcn_global_load_lds(
      (const __attribute__((address_space(1))) void*)g,
      (__attribute__((address_space(3))) void*)l, 16, 0, 0);
}

// ---------------- K0: Wb = bf16(W), layout unchanged [o][f] ----------------
__global__ __launch_bounds__(256) void k_wb(const float* __restrict__ W,
                                            u16* __restrict__ Wb) {
  int idx = (blockIdx.x * 256 + threadIdx.x) * 4;
  f32x4 v = *reinterpret_cast<const f32x4*>(W + idx);
  ushort4 o;
  o.x = f2bf_rne(v.x); o.y = f2bf_rne(v.y); o.z = f2bf_rne(v.z); o.w = f2bf_rne(v.w);
  *reinterpret_cast<ushort4*>(Wb + idx) = o;
}

// ------- K1: rowsum -> dis[i] = rsqrt(rowsum)  (R1-proven, pure read) -------
__global__ __launch_bounds__(256) void k_rowsum(const float* __restrict__ adj,
                                                float* __restrict__ dis) {
  const int row = blockIdx.x;
  const int t = threadIdx.x;
  const f32x4* p = reinterpret_cast<const f32x4*>(adj + (size_t)row * NN);
  float s = 0.f;
#pragma unroll
  for (int q = 0; q < 8; ++q) {
    f32x4 v = p[q * 256 + t];
    s += (v.x + v.y) + (v.z + v.w);
  }
#pragma unroll
  for (int o = 32; o > 0; o >>= 1) s += __shfl_down(s, o);
  __shared__ float red[4];
  if ((t & 63) == 0) red[t >> 6] = s;
  __syncthreads();
  if (t == 0) {
    float tot = (red[0] + red[1]) + (red[2] + red[3]);
    dis[row] = tot > 0.f ? 1.0f / sqrtf(tot) : 0.f;
  }
}

// ------- K2: xwT[fo][j] = bf16( dis[j] * (x @ W^T)[j][fo] )  (transposed) -------
// (R4-R16-verified) block: 32 j-rows x 256 fo, 4 waves.
__global__ __launch_bounds__(256) void k_xwt(const float* __restrict__ x,
                                             const float* __restrict__ dis,
                                             const u16* __restrict__ Wb,
                                             u16* __restrict__ xwT) {
  __shared__ __align__(16) u16 As[32 * 256];     // slot = r*32 + (c8^(r&7))
  __shared__ __align__(16) u16 LT[256 * 34];     // [fo][j], pad 34
  const int j0 = blockIdx.x * 32;
  const int t = threadIdx.x, lane = t & 63, w = t >> 6;
  const int wr = w >> 1, wc = w & 1;

#pragma unroll
  for (int q = 0; q < 4; ++q) {
    int chunk = t * 4 + q;           // 0..1023
    int r = chunk >> 5, c8 = chunk & 31;
    const float* g = x + (size_t)(j0 + r) * FF + c8 * 8;
    f32x4 v0 = *reinterpret_cast<const f32x4*>(g);
    f32x4 v1 = *reinterpret_cast<const f32x4*>(g + 4);
    float d = dis[j0 + r];
    s16x8 o;
#pragma unroll
    for (int e = 0; e < 4; ++e) o[e] = (short)f2bf_rne(v0[e] * d);
#pragma unroll
    for (int e = 0; e < 4; ++e) o[4 + e] = (short)f2bf_rne(v1[e] * d);
    *reinterpret_cast<s16x8*>(&As[(r * 32 + (c8 ^ (r & 7))) * 8]) = o;
  }
  __syncthreads();

  f32x4 occ[8] = {};
#pragma unroll
  for (int ks = 0; ks < 8; ++ks) {
    int cg = ks * 4 + (lane >> 4);
    int ar = wr * 16 + (lane & 15);
    bf16x8 af = __builtin_bit_cast(bf16x8,
        *reinterpret_cast<const s16x8*>(&As[(ar * 32 + (cg ^ (ar & 7))) * 8]));
#pragma unroll
    for (int ni = 0; ni < 8; ++ni) {
      int n = wc * 128 + ni * 16 + (lane & 15);
      bf16x8 bfv = __builtin_bit_cast(bf16x8,
          *reinterpret_cast<const s16x8*>(Wb + (size_t)n * FF + cg * 8));
      occ[ni] = __builtin_amdgcn_mfma_f32_16x16x32_bf16(af, bfv, occ[ni], 0, 0, 0);
    }
  }

  int rj0 = wr * 16 + (lane >> 4) * 4;
#pragma unroll
  for (int ni = 0; ni < 8; ++ni) {
    int c = wc * 128 + ni * 16 + (lane & 15);
#pragma unroll
    for (int e = 0; e < 4; ++e)
      LT[c * 34 + rj0 + e] = f2bf_rne(occ[ni][e]);
  }
  __syncthreads();

  {
    int fo = t, base = fo * 34;
    u16* dst = xwT + (size_t)fo * NN + j0;
#pragma unroll
    for (int q = 0; q < 4; ++q) {
      ushort4 vv;
      vv.x = LT[base + q * 8 + 0]; vv.y = LT[base + q * 8 + 1];
      vv.z = LT[base + q * 8 + 2]; vv.w = LT[base + q * 8 + 3];
      ushort4 vw;
      vw.x = LT[base + q * 8 + 4]; vw.y = LT[base + q * 8 + 5];
      vw.z = LT[base + q * 8 + 6]; vw.w = LT[base + q * 8 + 7];
      *reinterpret_cast<ushort4*>(dst + q * 8) = vv;
      *reinterpret_cast<ushort4*>(dst + q * 8 + 4) = vw;
    }
  }
}

// -------- K3: split-K GEMM  partb[kc] = bf16( adj_fp32_tile @ xwT^T ) --------
// Best-measured configuration (R9/R13, 128.8us): BM=128 BN=256 BK=64, kc=4,
// grid (4,64) -> kc fixed per XCD (B-window 1MB L2-resident), 512 thr,
// 8 waves 64x64, acc 4x4, 2:1 MFMA:ds_read. A = fp32 (L3-hot after rowsum),
// native-cvt repack in writeA.
__global__ __launch_bounds__(512, 2) void k_gemm1(const float* __restrict__ adj,
                                                  const u16* __restrict__ xwT,
                                                  u16* __restrict__ partb) {
  __shared__ __align__(16) u16 As[2][128 * 64];
  __shared__ __align__(16) u16 Bs[2][256 * 64];
  const int kc = blockIdx.x;            // 0..3
  const int bm = blockIdx.y;            // 0..63
  const size_t i0 = (size_t)bm * 128;
  const int k0 = kc * 2048;
  const int t = threadIdx.x;
  const int lane = t & 63;
  const int w = t >> 6;                 // 0..7
  const int wr = w >> 2;                // 0..1 (64 rows each)
  const int wc = w & 3;                 // 0..3 (64 cols each)

  f32x4 acc[4][4] = {};
  f32x4 areg[2][2];

  auto loadA = [&](int kt) {
#pragma unroll
    for (int q = 0; q < 2; ++q) {
      int cid = q * 512 + t;
      int r = cid >> 3, c = cid & 7;
      const float* g = adj + (i0 + r) * (size_t)NN + (k0 + kt * 64 + c * 8);
      areg[q][0] = *reinterpret_cast<const f32x4*>(g);
      areg[q][1] = *reinterpret_cast<const f32x4*>(g + 4);
    }
  };
  auto writeA = [&](int buf) {
#pragma unroll
    for (int q = 0; q < 2; ++q) {
      int cid = q * 512 + t;
      int r = cid >> 3, c = cid & 7;
      int slot = r * 8 + (c ^ (r & 7));   // XOR-swizzle (T2 / G4)
      bf16x8 o;
#pragma unroll
      for (int e = 0; e < 4; ++e) o[e] = (__bf16)areg[q][0][e];
#pragma unroll
      for (int e = 0; e < 4; ++e) o[4 + e] = (__bf16)areg[q][1][e];
      *reinterpret_cast<bf16x8*>(&As[buf][slot * 8]) = o;
    }
  };
  auto stageB = [&](int buf, int kt) {
#pragma unroll
    for (int q = 0; q < 4; ++q) {
      int s = (w * 4 + q) * 64 + lane;
      int r = s >> 3, pp = s & 7;
      int c = pp ^ (r & 7);               // inverse swizzle on global source
      const u16* g = xwT + (size_t)r * NN + (k0 + kt * 64 + c * 8);
      gld_lds16(g, &Bs[buf][(w * 4 + q) * 512]);
    }
  };
  auto compute = [&](int buf) {
#pragma unroll
    for (int kk = 0; kk < 2; ++kk) {
      const int cg = kk * 4 + (lane >> 4);
      bf16x8 af[4], bfv[4];
#pragma unroll
      for (int mi = 0; mi < 4; ++mi) {
        int r = wr * 64 + mi * 16 + (lane & 15);
        af[mi] = __builtin_bit_cast(bf16x8,
            *reinterpret_cast<const s16x8*>(&As[buf][(r * 8 + (cg ^ (r & 7))) * 8]));
      }
#pragma unroll
      for (int ni = 0; ni < 4; ++ni) {
        int n = wc * 64 + ni * 16 + (lane & 15);
        bfv[ni] = __builtin_bit_cast(bf16x8,
            *reinterpret_cast<const s16x8*>(&Bs[buf][(n * 8 + (cg ^ (n & 7))) * 8]));
      }
#pragma unroll
      for (int mi = 0; mi < 4; ++mi)
#pragma unroll
        for (int ni = 0; ni < 4; ++ni)
          acc[mi][ni] = __builtin_amdgcn_mfma_f32_16x16x32_bf16(af[mi], bfv[ni], acc[mi][ni], 0, 0, 0);
    }
  };

  loadA(0);
  stageB(0, 0);
  writeA(0);
  __syncthreads();
#pragma unroll 2
  for (int kt = 0; kt < 32; ++kt) {
    int buf = kt & 1;
    if (kt + 1 < 32) {
      loadA(kt + 1);
      stageB(buf ^ 1, kt + 1);
    }
    compute(buf);
    if (kt + 1 < 32) writeA(buf ^ 1);
    __syncthreads();
  }

  u16* pout = partb + (size_t)kc * ((size_t)NN * FF);
#pragma unroll
  for (int mi = 0; mi < 4; ++mi) {
    int rbase = wr * 64 + mi * 16 + ((lane >> 4) * 4);
#pragma unroll
    for (int ni = 0; ni < 4; ++ni) {
      int cc = wc * 64 + ni * 16 + (lane & 15);
#pragma unroll
      for (int e = 0; e < 4; ++e)
        pout[(i0 + rbase + e) * FF + cc] = f2bf_rne(acc[mi][ni][e]);
    }
  }
}

// -------- K4: out = dis_i * sum_kc partb + bias  (bf16 slices, fp32 out) --------
__global__ __launch_bounds__(256) void k_out_lite(const u16* __restrict__ partb,
                                                  const float* __restrict__ dis,
                                                  const float* __restrict__ bias,
                                                  float* __restrict__ out) {
  size_t base = ((size_t)blockIdx.x * 256 + threadIdx.x) * 8;
  int i = (int)(base >> 8);
  int c = (int)(base & 255);
  const size_t SL = (size_t)NN * FF;
  s16x8 a0 = *reinterpret_cast<const s16x8*>(partb + base);
  s16x8 a1 = *reinterpret_cast<const s16x8*>(partb + SL + base);
  s16x8 a2 = *reinterpret_cast<const s16x8*>(partb + 2 * SL + base);
  s16x8 a3 = *reinterpret_cast<const s16x8*>(partb + 3 * SL + base);
  float d = dis[i];
  f32x4 o0, o1;
#pragma unroll
  for (int e = 0; e < 4; ++e) {
    float s = (bf2f((u16)a0[e]) + bf2f((u16)a1[e]))
            + (bf2f((u16)a2[e]) + bf2f((u16)a3[e]));
    o0[e] = s * d + bias[c + e];
  }
#pragma unroll
  for (int e = 0; e < 4; ++e) {
    float s = (bf2f((u16)a0[4 + e]) + bf2f((u16)a1[4 + e]))
            + (bf2f((u16)a2[4 + e]) + bf2f((u16)a3[4 + e]));
    o1[e] = s * d + bias[c + 4 + e];
  }
  *reinterpret_cast<f32x4*>(out + base) = o0;
  *reinterpret_cast<f32x4*>(out + base + 4) = o1;
}

extern "C" void kernel_launch(void* const* d_in, const int* in_sizes, int n_in,
                              void* d_out, int out_size, void* d_ws, size_t ws_size,
                              hipStream_t stream) {
  (void)in_sizes; (void)n_in; (void)out_size; (void)ws_size;
  const float* x   = (const float*)d_in[0];
  const float* adj = (const float*)d_in[1];
  const float* W   = (const float*)d_in[2];
  const float* b   = (const float*)d_in[3];
  float* out = (float*)d_out;
  char* ws = (char*)d_ws;

  // ws: dis 32KB @0 | Wb 128KB @64KB | xwT 4MB @1MB | partb 16MB @8MB
  float* dis   = (float*)ws;
  u16*   Wb    = (u16*)(ws + (64u << 10));
  u16*   xwT   = (u16*)(ws + (1u << 20));
  u16*   partb = (u16*)(ws + (8u << 20));

  k_wb<<<dim3(64), dim3(256), 0, stream>>>(W, Wb);
  k_rowsum<<<dim3(8192), dim3(256), 0, stream>>>(adj, dis);
  k_xwt<<<dim3(256), dim3(256), 0, stream>>>(x, dis, Wb, xwT);
  k_gemm1<<<dim3(4, 64), dim3(512), 0, stream>>>(adj, xwT, partb);
  k_out_lite<<<dim3(1024), dim3(256), 0, stream>>>(partb, dis, b, out);
}